// Round 1
// baseline (151.885 us; speedup 1.0000x reference)
//
#include <hip/hip_runtime.h>

typedef unsigned short u16;
typedef unsigned int u32;
typedef __attribute__((ext_vector_type(8))) short bf16x8;
typedef __attribute__((ext_vector_type(4))) short bf16x4v;
typedef __attribute__((ext_vector_type(4))) float f32x4;

#define NWAYS 10
#define NC 128
#define NHW 1024

__device__ __forceinline__ u16 f2bf(float f) {
  u32 u = __builtin_bit_cast(u32, f);
  return (u16)((u + 0x7fffu + ((u >> 16) & 1u)) >> 16);  // RNE
}
__device__ __forceinline__ float bf2f(u16 h) {
  u32 u = ((u32)h) << 16;
  return __builtin_bit_cast(float, u);
}

// ---------------- Kernel 1: rnorm[b,c] = 1/||q[b,c,:]|| ----------------
__global__ __launch_bounds__(256) void k_rnorm(const float* __restrict__ q,
                                               float* __restrict__ rnorm) {
  int w = threadIdx.x >> 6, l = threadIdx.x & 63;
  int row = blockIdx.x * 4 + w;  // 0..8191
  const float* p = q + (size_t)row * NHW;
  float ss = 0.f;
#pragma unroll
  for (int k = 0; k < 4; ++k) {
    float4 v = *(const float4*)(p + k * 256 + l * 4);
    ss += v.x * v.x + v.y * v.y + v.z * v.z + v.w * v.w;
  }
#pragma unroll
  for (int m = 1; m <= 32; m <<= 1) ss += __shfl_xor(ss, m, 64);
  if (l == 0) rnorm[row] = 1.0f / sqrtf(ss);
}

// ---------------- Kernel 2: raw Gram G[j,c,d] += sum_n s_c s_d ; msum[j,c] += sum_n s_c ----
// grid = 10 classes * 20 chunks of 256 n ; block 256
__global__ __launch_bounds__(256) void k_covg(const float* __restrict__ sup,
                                              float* __restrict__ G,
                                              float* __restrict__ msum) {
  __shared__ u16 tile[NC * 256];  // swizzled [c][n], 64 KiB
  int j = blockIdx.x / 20, chunk = blockIdx.x % 20;
  int shot = chunk >> 2, p0 = (chunk & 3) * 256;
  int t = threadIdx.x;
  int c = t >> 1, half = t & 1;
  const float* src = sup + (((size_t)(j * 5 + shot) * NC + c) * NHW) + p0 + half * 128;
  float rowsum = 0.f;
#pragma unroll 4
  for (int it = 0; it < 32; ++it) {
    float4 v = *(const float4*)(src + it * 4);
    int nl = half * 128 + it * 4;
    int idx = c * 256 + (((nl >> 3) ^ (c & 15)) << 3) + (nl & 7);
    bf16x4v h;
    h[0] = (short)f2bf(v.x); h[1] = (short)f2bf(v.y);
    h[2] = (short)f2bf(v.z); h[3] = (short)f2bf(v.w);
    *(bf16x4v*)&tile[idx] = h;
    rowsum += v.x + v.y + v.z + v.w;
  }
  atomicAdd(&msum[j * NC + c], rowsum);
  __syncthreads();

  int w = t >> 6, l = t & 63, lr = l & 15, lg = l >> 4;
  f32x4 acc[2][8];
#pragma unroll
  for (int a = 0; a < 2; ++a)
#pragma unroll
    for (int bt = 0; bt < 8; ++bt) acc[a][bt] = (f32x4){0.f, 0.f, 0.f, 0.f};
#pragma unroll 1
  for (int kb = 0; kb < 8; ++kb) {
    int nn = kb * 32 + lg * 8;
    bf16x8 frag[8];
#pragma unroll
    for (int ti = 0; ti < 8; ++ti) {
      int cc = ti * 16 + lr;
      frag[ti] = *(const bf16x8*)&tile[cc * 256 + (((nn >> 3) ^ (cc & 15)) << 3)];
    }
    bf16x8 fa[2];  // A-operands loaded directly (avoid runtime-indexed reg array)
#pragma unroll
    for (int a = 0; a < 2; ++a) {
      int cc = (2 * w + a) * 16 + lr;
      fa[a] = *(const bf16x8*)&tile[cc * 256 + (((nn >> 3) ^ (cc & 15)) << 3)];
    }
#pragma unroll
    for (int a = 0; a < 2; ++a)
#pragma unroll
      for (int bt = 0; bt < 8; ++bt)
        acc[a][bt] = __builtin_amdgcn_mfma_f32_16x16x32_bf16(fa[a], frag[bt], acc[a][bt], 0, 0, 0);
  }
#pragma unroll
  for (int a = 0; a < 2; ++a)
#pragma unroll
    for (int bt = 0; bt < 8; ++bt)
#pragma unroll
      for (int r = 0; r < 4; ++r) {
        int cr = (2 * w + a) * 16 + lg * 4 + r;  // C/D: row=(lane>>4)*4+reg
        int d = bt * 16 + lr;                    //      col=lane&15
        atomicAdd(&G[((size_t)j * NC + cr) * NC + d], acc[a][bt][r]);
      }
}

// ---------------- Kernel 3: cov_bf16 = (G - msum_c*msum_d/N)/(N-1) ----------------
__global__ __launch_bounds__(256) void k_fin(const float* __restrict__ G,
                                             const float* __restrict__ msum,
                                             u16* __restrict__ covb) {
  int idx = blockIdx.x * 256 + threadIdx.x;  // < 163840
  int j = idx >> 14, rem = idx & 16383, c = rem >> 7, d = rem & 127;
  float v = (G[idx] - msum[j * NC + c] * msum[j * NC + d] * (1.0f / 5120.0f)) * (1.0f / 5119.0f);
  covb[idx] = f2bf(v);
}

// ---------------- Kernel 4: main fused sim + leaky + conv ----------------
// grid = 64 b * 8 pixel-chunks of 128 ; block 128 (2 waves)
__global__ __launch_bounds__(128, 1) void k_main(const float* __restrict__ q,
                                                 const u16* __restrict__ covb,
                                                 const float* __restrict__ rnorm,
                                                 const float* __restrict__ cw,
                                                 float* __restrict__ out) {
  __shared__ u16 lds[2][NC * 128];  // 2 x 32 KiB: cov double-buffer; [1] holds qn first
  int bid = blockIdx.x;
  int b = bid >> 3, pc = bid & 7;
  int t = threadIdx.x;  // 0..127 == local pixel for staging
  int w = t >> 6, l = t & 63, lr = l & 15, lg = l >> 4;

  // stage normalized q tile (bf16) into lds[1], layout [p][c] XOR-swizzled
  {
    const float* qp = q + (size_t)b * NC * NHW + pc * 128 + t;
#pragma unroll 8
    for (int c = 0; c < NC; ++c) {
      float v = qp[(size_t)c * NHW] * rnorm[b * NC + c];
      lds[1][t * 128 + (((c >> 3) ^ (t & 15)) << 3) + (c & 7)] = f2bf(v);
    }
  }
  __syncthreads();

  // per-wave persistent fragments (j-invariant): B-frags + diag-multiply values
  bf16x8 Ball[4][4];
  bf16x4v qnm[4][8];
  int ptb = w * 4;
#pragma unroll
  for (int pt = 0; pt < 4; ++pt) {
    int p = (ptb + pt) * 16 + lr;
#pragma unroll
    for (int kt = 0; kt < 4; ++kt) {
      int d0 = kt * 32 + lg * 8;
      Ball[pt][kt] = *(const bf16x8*)&lds[1][p * 128 + (((d0 >> 3) ^ (p & 15)) << 3)];
    }
#pragma unroll
    for (int ct = 0; ct < 8; ++ct) {
      int c0 = ct * 16 + lg * 4;
      qnm[pt][ct] = *(const bf16x4v*)&lds[1][p * 128 + (((c0 >> 3) ^ (p & 15)) << 3) + (c0 & 7)];
    }
  }
  float wv[4];
#pragma unroll
  for (int pt = 0; pt < 4; ++pt) wv[pt] = cw[pc * 128 + (ptb + pt) * 16 + lr];

  // stage cov_0 into lds[0] (16B-unit copy, swizzle preserves 16B granularity)
  {
    const uint4* src = (const uint4*)covb;
#pragma unroll
    for (int k = 0; k < 16; ++k) {
      int u = t + k * 128;
      uint4 v = src[u];
      int c = u >> 4, col = u & 15;
      *(uint4*)&lds[0][c * 128 + ((col ^ (c & 15)) << 3)] = v;
    }
  }
  __syncthreads();

#pragma unroll 1
  for (int j = 0; j < NWAYS; ++j) {
    const u16* buf = lds[j & 1];
    uint4 nxt[16];
    if (j < NWAYS - 1) {  // issue next-cov loads early (hide under MFMA)
      const uint4* src = (const uint4*)covb + (size_t)(j + 1) * 2048;
#pragma unroll
      for (int k = 0; k < 16; ++k) nxt[k] = src[t + k * 128];
    }
    f32x4 acc[8][4];
#pragma unroll
    for (int ct = 0; ct < 8; ++ct)
#pragma unroll
      for (int pt = 0; pt < 4; ++pt) acc[ct][pt] = (f32x4){0.f, 0.f, 0.f, 0.f};
#pragma unroll 1
    for (int kt = 0; kt < 4; ++kt) {
      bf16x8 A[8];
#pragma unroll
      for (int ct = 0; ct < 8; ++ct) {
        int c = ct * 16 + lr;
        int col = (kt * 4 + lg) ^ (c & 15);
        A[ct] = *(const bf16x8*)&buf[c * 128 + (col << 3)];
      }
#pragma unroll
      for (int ct = 0; ct < 8; ++ct)
#pragma unroll
        for (int pt = 0; pt < 4; ++pt)
          acc[ct][pt] = __builtin_amdgcn_mfma_f32_16x16x32_bf16(A[ct], Ball[pt][kt], acc[ct][pt], 0, 0, 0);
    }
    // epilogue: sim = sum_c qn*T per pixel, leaky, dot with conv_w
    float sj = 0.f;
#pragma unroll
    for (int pt = 0; pt < 4; ++pt) {
      float s = 0.f;
#pragma unroll
      for (int ct = 0; ct < 8; ++ct) {
        f32x4 a = acc[ct][pt];
        bf16x4v qm = qnm[pt][ct];
        s += a[0] * bf2f((u16)qm[0]) + a[1] * bf2f((u16)qm[1]) +
             a[2] * bf2f((u16)qm[2]) + a[3] * bf2f((u16)qm[3]);
      }
      s += __shfl_xor(s, 16, 64);
      s += __shfl_xor(s, 32, 64);  // full sim[p], replicated x4
      s = (s >= 0.f) ? s : 0.2f * s;
      sj += s * wv[pt];
    }
#pragma unroll
    for (int m = 1; m <= 32; m <<= 1) sj += __shfl_xor(sj, m, 64);
    if (l == 0) atomicAdd(&out[b * NWAYS + j], sj * 0.25f);  // /4: each pixel counted 4x
    if (j < NWAYS - 1) {  // write next cov into the other buffer
      u16* dst = lds[(j + 1) & 1];
#pragma unroll
      for (int k = 0; k < 16; ++k) {
        int u = t + k * 128;
        int c = u >> 4, col = u & 15;
        *(uint4*)&dst[c * 128 + ((col ^ (c & 15)) << 3)] = nxt[k];
      }
    }
    __syncthreads();
  }
}

extern "C" void kernel_launch(void* const* d_in, const int* in_sizes, int n_in,
                              void* d_out, int out_size, void* d_ws, size_t ws_size,
                              hipStream_t stream) {
  (void)in_sizes; (void)n_in; (void)out_size; (void)ws_size;
  const float* q = (const float*)d_in[0];
  const float* sup = (const float*)d_in[1];
  const float* cw = (const float*)d_in[2];
  float* out = (float*)d_out;

  float* G = (float*)d_ws;           // 163840 f32
  float* msum = G + 163840;          // 1280 f32
  float* rnorm = msum + 1280;        // 8192 f32
  u16* covb = (u16*)(rnorm + 8192);  // 163840 u16  (total ~1.02 MB of ws)

  hipMemsetAsync(d_ws, 0, (163840 + 1280) * sizeof(float), stream);
  hipMemsetAsync(d_out, 0, 64 * NWAYS * sizeof(float), stream);
  k_rnorm<<<2048, 256, 0, stream>>>(q, rnorm);
  k_covg<<<200, 256, 0, stream>>>(sup, G, msum);
  k_fin<<<640, 256, 0, stream>>>(G, msum, covb);
  k_main<<<512, 128, 0, stream>>>(q, covb, rnorm, cw, out);
}

// Round 2
// 69.413 us; speedup vs baseline: 2.1881x; 2.1881x over previous
//
#include <hip/hip_runtime.h>

typedef unsigned short u16;
typedef unsigned int u32;
typedef __attribute__((ext_vector_type(8))) short bf16x8;
typedef __attribute__((ext_vector_type(4))) short bf16x4v;
typedef __attribute__((ext_vector_type(4))) float f32x4;

#define NWAYS 10
#define NC 128
#define NHW 1024

__device__ __forceinline__ u16 f2bf(float f) {
  u32 u = __builtin_bit_cast(u32, f);
  return (u16)((u + 0x7fffu + ((u >> 16) & 1u)) >> 16);  // RNE
}

// ---------------- Kernel 1: raw Gram G[j,c,d] += sum_n s_c s_d ; msum[j,c] += sum_n s_c ----
// grid = 10 classes * 20 chunks of 256 n ; block 256
__global__ __launch_bounds__(256) void k_covg(const float* __restrict__ sup,
                                              float* __restrict__ G,
                                              float* __restrict__ msum) {
  __shared__ u16 tile[NC * 256];  // swizzled [c][n], 64 KiB
  int j = blockIdx.x / 20, chunk = blockIdx.x % 20;
  int shot = chunk >> 2, p0 = (chunk & 3) * 256;
  int t = threadIdx.x;
  int c = t >> 1, half = t & 1;
  const float* src = sup + (((size_t)(j * 5 + shot) * NC + c) * NHW) + p0 + half * 128;
  float rowsum = 0.f;
#pragma unroll 4
  for (int it = 0; it < 32; ++it) {
    float4 v = *(const float4*)(src + it * 4);
    int nl = half * 128 + it * 4;
    int idx = c * 256 + (((nl >> 3) ^ (c & 15)) << 3) + (nl & 7);
    bf16x4v h;
    h[0] = (short)f2bf(v.x); h[1] = (short)f2bf(v.y);
    h[2] = (short)f2bf(v.z); h[3] = (short)f2bf(v.w);
    *(bf16x4v*)&tile[idx] = h;
    rowsum += v.x + v.y + v.z + v.w;
  }
  atomicAdd(&msum[j * NC + c], rowsum);
  __syncthreads();

  int w = t >> 6, l = t & 63, lr = l & 15, lg = l >> 4;
  f32x4 acc[2][8];
#pragma unroll
  for (int a = 0; a < 2; ++a)
#pragma unroll
    for (int bt = 0; bt < 8; ++bt) acc[a][bt] = (f32x4){0.f, 0.f, 0.f, 0.f};
#pragma unroll 1
  for (int kb = 0; kb < 8; ++kb) {
    int nn = kb * 32 + lg * 8;
    bf16x8 frag[8];
#pragma unroll
    for (int ti = 0; ti < 8; ++ti) {
      int cc = ti * 16 + lr;
      frag[ti] = *(const bf16x8*)&tile[cc * 256 + (((nn >> 3) ^ (cc & 15)) << 3)];
    }
    bf16x8 fa[2];
#pragma unroll
    for (int a = 0; a < 2; ++a) {
      int cc = (2 * w + a) * 16 + lr;
      fa[a] = *(const bf16x8*)&tile[cc * 256 + (((nn >> 3) ^ (cc & 15)) << 3)];
    }
#pragma unroll
    for (int a = 0; a < 2; ++a)
#pragma unroll
      for (int bt = 0; bt < 8; ++bt)
        acc[a][bt] = __builtin_amdgcn_mfma_f32_16x16x32_bf16(fa[a], frag[bt], acc[a][bt], 0, 0, 0);
  }
#pragma unroll
  for (int a = 0; a < 2; ++a)
#pragma unroll
    for (int bt = 0; bt < 8; ++bt)
#pragma unroll
      for (int r = 0; r < 4; ++r) {
        int cr = (2 * w + a) * 16 + lg * 4 + r;  // C/D: row=(lane>>4)*4+reg
        int d = bt * 16 + lr;                    //      col=lane&15
        atomicAdd(&G[((size_t)j * NC + cr) * NC + d], acc[a][bt][r]);
      }
}

// ---------------- Kernel 2: in-place fp32 cov = (G - msum_c*msum_d/N)/(N-1) ----------------
__global__ __launch_bounds__(256) void k_fin(float* __restrict__ G,
                                             const float* __restrict__ msum) {
  int idx = blockIdx.x * 256 + threadIdx.x;  // < 163840
  int j = idx >> 14, rem = idx & 16383, c = rem >> 7, d = rem & 127;
  G[idx] = (G[idx] - msum[j * NC + c] * msum[j * NC + d] * (1.0f / 5120.0f)) * (1.0f / 5119.0f);
}

// ---------------- Kernel 3: weighted q-Gram: Wraw[b,c,d] += sum_p w_p q_c q_d ; ss[b,c] += sum_p q_c^2 ----
// grid = 64 b * 2 halves of 512 p ; block 512 (8 waves); each block loops 4 chunks of 128 p
__global__ __launch_bounds__(512) void k_wgram(const float* __restrict__ q,
                                               const float* __restrict__ cw,
                                               float* __restrict__ Wraw,
                                               float* __restrict__ ss) {
  __shared__ u16 traw[NC * 128];  // 32 KiB [c][128p] swizzled
  __shared__ u16 twgt[NC * 128];  // 32 KiB, w_p-scaled
  __shared__ float ss_loc[NC];
  int bid = blockIdx.x;
  int b = bid >> 1, pc = bid & 1;
  int t = threadIdx.x;
  int w = t >> 6, l = t & 63, lr = l & 15, lg = l >> 4;
  if (t < NC) ss_loc[t] = 0.f;
  const float* base = q + (size_t)b * NC * NHW + pc * 512;
  const float* cwb = cw + pc * 512;

  float4 v[8];
  auto load_chunk = [&](int chunk) {
#pragma unroll
    for (int it = 0; it < 8; ++it) {
      int idx = it * 512 + t;
      int c = idx >> 5, pos = idx & 31;  // 32 float4 per 128-p row: full-row coalescing
      v[it] = *(const float4*)(base + (size_t)c * NHW + chunk * 128 + pos * 4);
    }
  };
  auto store_chunk = [&](int chunk) {
#pragma unroll
    for (int it = 0; it < 8; ++it) {
      int idx = it * 512 + t;
      int c = idx >> 5, pos = idx & 31;
      float4 vv = v[it];
      float4 wv = *(const float4*)(cwb + chunk * 128 + pos * 4);
      int nl = pos * 4;
      int off = c * 128 + (((nl >> 3) ^ (c & 15)) << 3) + (nl & 7);
      bf16x4v hr, hw;
      hr[0] = (short)f2bf(vv.x); hr[1] = (short)f2bf(vv.y);
      hr[2] = (short)f2bf(vv.z); hr[3] = (short)f2bf(vv.w);
      hw[0] = (short)f2bf(vv.x * wv.x); hw[1] = (short)f2bf(vv.y * wv.y);
      hw[2] = (short)f2bf(vv.z * wv.z); hw[3] = (short)f2bf(vv.w * wv.w);
      *(bf16x4v*)&traw[off] = hr;
      *(bf16x4v*)&twgt[off] = hw;
      float s = vv.x * vv.x + vv.y * vv.y + vv.z * vv.z + vv.w * vv.w;
#pragma unroll
      for (int m = 1; m <= 16; m <<= 1) s += __shfl_xor(s, m, 64);
      if ((l & 31) == 0) ss_loc[c] += s;  // unique writer per row per it (no race)
    }
  };

  load_chunk(0);
  store_chunk(0);
  __syncthreads();

  f32x4 acc[8];
#pragma unroll
  for (int bt = 0; bt < 8; ++bt) acc[bt] = (f32x4){0.f, 0.f, 0.f, 0.f};

#pragma unroll 1
  for (int chunk = 0; chunk < 4; ++chunk) {
    if (chunk < 3) load_chunk(chunk + 1);  // issue-early: HBM hides under MFMA
#pragma unroll
    for (int kb = 0; kb < 4; ++kb) {
      int nn = kb * 32 + lg * 8;
      int arow = w * 16 + lr;  // wave owns 16 rows of W
      bf16x8 fa = *(const bf16x8*)&twgt[arow * 128 + (((nn >> 3) ^ (arow & 15)) << 3)];
      bf16x8 fb[8];
#pragma unroll
      for (int bt = 0; bt < 8; ++bt) {
        int drow = bt * 16 + lr;
        fb[bt] = *(const bf16x8*)&traw[drow * 128 + (((nn >> 3) ^ (drow & 15)) << 3)];
      }
#pragma unroll
      for (int bt = 0; bt < 8; ++bt)
        acc[bt] = __builtin_amdgcn_mfma_f32_16x16x32_bf16(fa, fb[bt], acc[bt], 0, 0, 0);
    }
    __syncthreads();
    if (chunk < 3) { store_chunk(chunk + 1); __syncthreads(); }
  }

  if (t < NC) atomicAdd(&ss[b * NC + t], ss_loc[t]);
  float* wb = Wraw + ((size_t)b << 14);
#pragma unroll
  for (int bt = 0; bt < 8; ++bt)
#pragma unroll
    for (int r = 0; r < 4; ++r) {
      int cr = w * 16 + lg * 4 + r;
      int d = bt * 16 + lr;
      atomicAdd(&wb[cr * 128 + d], acc[bt][r]);
    }
}

// ---------------- Kernel 4: out[b,j] = sum_cd cov_j[c,d] * rn_c * rn_d * Wraw_b[c,d] ----
// grid = 640 (b*10+j) ; block 256
__global__ __launch_bounds__(256) void k_final(const float* __restrict__ covf,
                                               const float* __restrict__ Wraw,
                                               const float* __restrict__ ss,
                                               float* __restrict__ out) {
  __shared__ float rnl[NC];
  __shared__ float wred[4];
  int bid = blockIdx.x;
  int b = bid / NWAYS, j = bid - b * NWAYS;
  int t = threadIdx.x;
  if (t < NC) rnl[t] = rsqrtf(ss[b * NC + t]);
  __syncthreads();
  const float* cj = covf + (size_t)j * 16384;
  const float* wb = Wraw + ((size_t)b << 14);
  float rd = rnl[t & 127];  // d = idx&127 == t&127, constant per thread
  float sum = 0.f;
#pragma unroll 8
  for (int i = 0; i < 64; ++i) {
    int idx = i * 256 + t;
    sum += cj[idx] * wb[idx] * rnl[idx >> 7];
  }
  sum *= rd;
#pragma unroll
  for (int m = 1; m <= 32; m <<= 1) sum += __shfl_xor(sum, m, 64);
  if ((t & 63) == 0) wred[t >> 6] = sum;
  __syncthreads();
  if (t == 0) out[bid] = wred[0] + wred[1] + wred[2] + wred[3];
}

extern "C" void kernel_launch(void* const* d_in, const int* in_sizes, int n_in,
                              void* d_out, int out_size, void* d_ws, size_t ws_size,
                              hipStream_t stream) {
  (void)in_sizes; (void)n_in; (void)out_size; (void)ws_size;
  const float* q = (const float*)d_in[0];
  const float* sup = (const float*)d_in[1];
  const float* cw = (const float*)d_in[2];
  float* out = (float*)d_out;

  float* G = (float*)d_ws;        // 163840 f32 (becomes fp32 cov in place)
  float* msum = G + 163840;       // 1280 f32
  float* ssb = msum + 1280;       // 8192 f32
  float* Wraw = ssb + 8192;       // 1048576 f32   (total ~4.89 MB of ws)

  hipMemsetAsync(d_ws, 0, (size_t)(163840 + 1280 + 8192 + 1048576) * sizeof(float), stream);
  k_covg<<<200, 256, 0, stream>>>(sup, G, msum);
  k_fin<<<640, 256, 0, stream>>>(G, msum);
  k_wgram<<<128, 512, 0, stream>>>(q, cw, Wraw, ssb);
  k_final<<<640, 256, 0, stream>>>(G, Wraw, ssb, out);
}